// Round 12
// baseline (40.389 us; speedup 1.0000x reference)
//
#include <hip/hip_runtime.h>

#define B_ 4
#define C_ 64
#define H_ 128
#define W_ 128
#define O_ 64
#define KK_ 9
#define OFFC_ 18
#define HW_ (H_*W_)
#define VSB 1152   // val row stride in bytes (576 fp16)

typedef __attribute__((ext_vector_type(8))) _Float16 h8;
typedef __attribute__((ext_vector_type(4))) _Float16 h4;
typedef __attribute__((ext_vector_type(2))) __fp16 fp16x2;
typedef __attribute__((ext_vector_type(4))) float f32x4;

// ---------- kernel 1: transpose x NCHW fp32 -> NHWC fp16, + weight prep ----------
__global__ __launch_bounds__(256) void k_pre(
    const float* __restrict__ x, const float* __restrict__ w_dcn,
    const float* __restrict__ w_off, _Float16* __restrict__ xt,
    _Float16* __restrict__ wb, _Float16* __restrict__ wboff)
{
    __shared__ float tile[C_][133];
    int blk = blockIdx.x;
    if (blk < 512) {
        const float* xp = x + (size_t)(blk >> 7) * C_ * HW_ + (blk & 127) * W_;
#pragma unroll
        for (int i = 0; i < 8; ++i) {
            int idx = threadIdx.x + i * 256;     // 0..2047 float4 slots
            int c = idx >> 5, w4 = idx & 31;
            float4 v = *(const float4*)(xp + c * HW_ + w4 * 4);
            tile[c][w4*4+0] = v.x; tile[c][w4*4+1] = v.y;
            tile[c][w4*4+2] = v.z; tile[c][w4*4+3] = v.w;
        }
        __syncthreads();
        _Float16* op = xt + (size_t)blk * (W_ * C_);
#pragma unroll
        for (int i = 0; i < 8; ++i) {
            int idx = threadIdx.x + i * 256;     // 0..2047 h4 slots
            int w = idx >> 4, c4 = idx & 15;
            h4 o;
            o.x = (_Float16)tile[c4*4+0][w]; o.y = (_Float16)tile[c4*4+1][w];
            o.z = (_Float16)tile[c4*4+2][w]; o.w = (_Float16)tile[c4*4+3][w];
            *(h4*)(op + w*64 + c4*4) = o;
        }
    } else {
        int i = (blk - 512) * 256 + threadIdx.x;
        if (i < O_ * 576) {
            int j = i & 7, l = (i >> 3) & 63, t = (i >> 9) % 18, ot = i / (18*512);
            int k = t*32 + ((l>>4)&3)*8 + j;
            int o = ot*16 + (l & 15);
            int kk = k >> 6, c = k & 63;
            wb[i] = (_Float16)w_dcn[(o*64 + c)*9 + kk];
        }
        int i2 = i - O_*576;
        if (i2 >= 0 && i2 < 32*576) {
            int j = i2 & 7, l = (i2 >> 3) & 63, t = (i2 >> 9) % 18, mt = i2 / (18*512);
            int k = t*32 + ((l>>4)&3)*8 + j;
            int o = mt*16 + (l & 15);
            int kk = k >> 6, c = k & 63;
            wboff[i2] = (o < OFFC_) ? (_Float16)w_off[(o*64 + c)*9 + kk] : (_Float16)0.f;
        }
    }
}

// producer: compute 4 corner byte-addrs + 2 packed fp16 weight words for (pixel p, tap kk_)
#define POSC(kk_, A0, A1, A2, A3, WL, WH) do { \
    int ki_ = (kk_) / 3, kj_ = (kk_) % 3; \
    float dy = offl[2*(kk_)][p]; \
    float dx = offl[2*(kk_)+1][p]; \
    float py = (float)(ho - 1 + ki_) + dy; \
    float px = (float)(wo - 1 + kj_) + dx; \
    float fy = floorf(py), fx = floorf(px); \
    int y0 = (int)fy, x0 = (int)fx; \
    float ly = py - fy, lx = px - fx; \
    int y1 = y0 + 1, x1 = x0 + 1; \
    float my0 = ((unsigned)y0 < H_) ? 1.f : 0.f; \
    float my1 = ((unsigned)y1 < H_) ? 1.f : 0.f; \
    float mx0 = ((unsigned)x0 < W_) ? 1.f : 0.f; \
    float mx1 = ((unsigned)x1 < W_) ? 1.f : 0.f; \
    int y0c = min(max(y0,0),H_-1), y1c = min(max(y1,0),H_-1); \
    int x0c = min(max(x0,0),W_-1), x1c = min(max(x1,0),W_-1); \
    A0 = (y0c*W_ + x0c)*128; A1 = (y0c*W_ + x1c)*128; \
    A2 = (y1c*W_ + x0c)*128; A3 = (y1c*W_ + x1c)*128; \
    union { fp16x2 h; unsigned u; } ul_, uh_; \
    ul_.h = __builtin_amdgcn_cvt_pkrtz((1.f-ly)*(1.f-lx)*my0*mx0, (1.f-ly)*lx*my0*mx1); \
    uh_.h = __builtin_amdgcn_cvt_pkrtz(ly*(1.f-lx)*my1*mx0, ly*lx*my1*mx1); \
    WL = ul_.u; WH = uh_.u; \
} while(0)

// consumer: pull tap kk_'s pos from producer lane, gather 8 ch, blend, swizzled store
#define TAP(kk_, A0, A1, A2, A3, WL, WH) do { \
    int s_ = (lbase | ((kk_) < 8 ? (kk_) : 0)) << 2; \
    int b0 = __builtin_amdgcn_ds_bpermute(s_, A0); \
    int b1 = __builtin_amdgcn_ds_bpermute(s_, A1); \
    int b2 = __builtin_amdgcn_ds_bpermute(s_, A2); \
    int b3 = __builtin_amdgcn_ds_bpermute(s_, A3); \
    union { unsigned u; fp16x2 h; } wl_, wh_; \
    wl_.u = (unsigned)__builtin_amdgcn_ds_bpermute(s_, (int)WL); \
    wh_.u = (unsigned)__builtin_amdgcn_ds_bpermute(s_, (int)WH); \
    h8 c0 = *(const h8*)(xbc + b0 + cg8*16); \
    h8 c1 = *(const h8*)(xbc + b1 + cg8*16); \
    h8 c2 = *(const h8*)(xbc + b2 + cg8*16); \
    h8 c3 = *(const h8*)(xbc + b3 + cg8*16); \
    _Float16 h00 = (_Float16)wl_.h[0], h01 = (_Float16)wl_.h[1]; \
    _Float16 h10 = (_Float16)wh_.h[0], h11 = (_Float16)wh_.h[1]; \
    h8 w00v = {h00,h00,h00,h00,h00,h00,h00,h00}; \
    h8 w01v = {h01,h01,h01,h01,h01,h01,h01,h01}; \
    h8 w10v = {h10,h10,h10,h10,h10,h10,h10,h10}; \
    h8 w11v = {h11,h11,h11,h11,h11,h11,h11,h11}; \
    h8 r_ = c0*w00v + c1*w01v + c2*w10v + c3*w11v; \
    *(h8*)(vb + ((((kk_)*8 + cg8) ^ ph) << 4)) = r_; \
} while(0)

// ---------- kernel 2: fused offset-conv + deformable conv, 32-px blocks ----------
// grid = B*H*4 = 2048, XCD-swizzled. LDS 39.4 KB -> 4 blocks/CU;
// launch_bounds(256,4) caps VGPR at 128 -> 4 waves/SIMD.
// P3 pos math deduplicated via in-wave ds_bpermute: each lane computes pos for
// its own pixel's tap (lane&7), consumers pull {4 addrs, 2 packed-weight words}.
__global__ __launch_bounds__(256, 4) void k_fused(
    const _Float16* __restrict__ xt, const _Float16* __restrict__ wb,
    const _Float16* __restrict__ wboff, const float* __restrict__ b_off,
    const float* __restrict__ b_dcn, float* __restrict__ out)
{
    __shared__ __align__(16) char val2[2][16 * VSB];    // 36864 B
    __shared__ __align__(16) float offl[OFFC_][33];     // 2376 B (padded: conflict-free strided reads)

    int tid = threadIdx.x;
    int d = blockIdx.x;
    int blk = (d & 7) * 256 + (d >> 3);   // XCD-contiguous chunks
    int wt2 = blk & 3, ho = (blk >> 2) & 127, b = blk >> 9;
    int wo0 = wt2 * 32;
    int wave = tid >> 6, lane = tid & 63;
    int mt = wave >> 1;          // M-tile for offset MFMA
    int rg_m = wave & 1;         // px region for offset MFMA
    const char* xbc = (const char*)xt + (size_t)b * HW_ * 128;

    // ---- P0: regular im2col gather for offset conv -> val2 ----
    {
        int cg8 = tid & 7, px32 = tid >> 3;
        int rg_f = px32 >> 4, p = px32 & 15, ph = p & 7;
        char* vb = &val2[rg_f][0] + p * VSB;
        int wo = wo0 + px32;
#pragma unroll 3
        for (int kk = 0; kk < KK_; ++kk) {
            int y = ho + kk/3 - 1;
            int xx = wo + kk%3 - 1;
            h8 v = {0,0,0,0,0,0,0,0};
            if ((unsigned)y < H_ && (unsigned)xx < W_)
                v = *(const h8*)(xbc + (y*W_ + xx)*128 + cg8*16);
            int g8 = kk*8 + cg8;
            *(h8*)(vb + ((g8 ^ ph) << 4)) = v;
        }
    }
    __syncthreads();

    // ---- P1: offset MFMA, wave=(mt,rg) -> offl ----
    {
        h8 aoff[18];
        const _Float16* wp = wboff + ((mt*18)*64 + lane)*8;
#pragma unroll
        for (int t = 0; t < 18; ++t) aoff[t] = *(const h8*)(wp + t*512);
        f32x4 acc = {0.f,0.f,0.f,0.f};
        const char* vb = &val2[rg_m][0] + (lane & 15) * VSB;
        int gk = (lane >> 4) & 3;
        int ph = (lane & 15) & 7;
#pragma unroll
        for (int t = 0; t < 18; ++t) {
            h8 bfr = *(const h8*)(vb + (((t*4 + gk) ^ ph) << 4));
            acc = __builtin_amdgcn_mfma_f32_16x16x32_f16(aoff[t], bfr, acc, 0, 0, 0);
        }
        int orow = mt*16 + gk*4;
#pragma unroll
        for (int r = 0; r < 4; ++r) {
            int o = orow + r;
            if (o < OFFC_)
                offl[o][rg_m*16 + (lane & 15)] = acc[r] + b_off[o];
        }
    }
    __syncthreads();

    // ---- P3: pos-share via bpermute + bilinear gather + blend ----
    {
        int cg8 = tid & 7, p = (tid >> 3) & 31;
        int ph = p & 7;
        char* vb = &val2[p >> 4][0] + (p & 15) * VSB;
        int wo = wo0 + p;
        int lbase = lane & 56;

        // producer: pos for (own pixel p, tap kt=lane&7); all lanes also produce tap 8
        int kt = tid & 7;
        int a0A, a1A, a2A, a3A, a0B, a1B, a2B, a3B;
        unsigned wlA, whA, wlB, whB;
        POSC(kt, a0A, a1A, a2A, a3A, wlA, whA);
        POSC(8,  a0B, a1B, a2B, a3B, wlB, whB);

        TAP(0, a0A, a1A, a2A, a3A, wlA, whA);
        TAP(1, a0A, a1A, a2A, a3A, wlA, whA);
        TAP(2, a0A, a1A, a2A, a3A, wlA, whA);
        TAP(3, a0A, a1A, a2A, a3A, wlA, whA);
        TAP(4, a0A, a1A, a2A, a3A, wlA, whA);
        TAP(5, a0A, a1A, a2A, a3A, wlA, whA);
        TAP(6, a0A, a1A, a2A, a3A, wlA, whA);
        TAP(7, a0A, a1A, a2A, a3A, wlA, whA);
        TAP(8, a0B, a1B, a2B, a3B, wlB, whB);
    }
    __syncthreads();

    // ---- P4: deform MFMA, wave w owns ch w*16..w*16+15, both px regions ----
    {
        h8 afr[18];
        const _Float16* wp = wb + ((wave*18)*64 + lane)*8;
#pragma unroll
        for (int t = 0; t < 18; ++t) afr[t] = *(const h8*)(wp + t*512);
        int gk = (lane >> 4) & 3;
        int ph = (lane & 15) & 7;
        int orow = wave*16 + gk*4;
#pragma unroll
        for (int rg = 0; rg < 2; ++rg) {
            f32x4 acc = {0.f,0.f,0.f,0.f};
            const char* vb = &val2[rg][0] + (lane & 15) * VSB;
#pragma unroll
            for (int t = 0; t < 18; ++t) {
                h8 bfr = *(const h8*)(vb + (((t*4 + gk) ^ ph) << 4));
                acc = __builtin_amdgcn_mfma_f32_16x16x32_f16(afr[t], bfr, acc, 0, 0, 0);
            }
            int wo = wo0 + rg*16 + (lane & 15);
#pragma unroll
            for (int r = 0; r < 4; ++r) {
                int o = orow + r;
                out[((b*O_ + o)*H_ + ho)*W_ + wo] = acc[r] + b_dcn[o];
            }
        }
    }
}

extern "C" void kernel_launch(void* const* d_in, const int* in_sizes, int n_in,
                              void* d_out, int out_size, void* d_ws, size_t ws_size,
                              hipStream_t stream) {
    const float* x     = (const float*)d_in[0];
    const float* w_off = (const float*)d_in[1];
    const float* b_off = (const float*)d_in[2];
    const float* w_dcn = (const float*)d_in[3];
    const float* b_dcn = (const float*)d_in[4];
    float* out = (float*)d_out;

    char* ws = (char*)d_ws;
    _Float16* xt   = (_Float16*)ws;                          // 8,388,608 B
    _Float16* wb   = (_Float16*)(ws + 8388608);              // 73,728 B
    _Float16* wboff = wb + O_*576;                           // 36,864 B

    k_pre<<<728, 256, 0, stream>>>(x, w_dcn, w_off, xt, wb, wboff);
    k_fused<<<B_ * H_ * 4, 256, 0, stream>>>(xt, wb, wboff, b_off, b_dcn, out);
}